// Round 6
// baseline (295.586 us; speedup 1.0000x reference)
//
#include <hip/hip_runtime.h>
#include <stdint.h>

#define T_TOK 2048
#define H_DIM 1024
#define E_NUM 16
#define I_DIM 1024
#define TOTAL_ROWS (2 * T_TOK)   // exactly T*K assignment rows
#define CPAD 16                  // counts padded to one per 64B cacheline

typedef short bf16x8 __attribute__((ext_vector_type(8)));
typedef float f32x4 __attribute__((ext_vector_type(4)));

__device__ __forceinline__ void async_copy16(const void* g, void* l) {
  __builtin_amdgcn_global_load_lds(
      (const __attribute__((address_space(1))) void*)g,
      (__attribute__((address_space(3))) void*)l, 16, 0, 0);
}

// fp32 -> bf16 round-to-nearest-even (inputs finite)
__device__ __forceinline__ uint32_t f2bf(float f) {
  uint32_t u = __float_as_uint(f);
  return (u + 0x7FFFu + ((u >> 16) & 1u)) >> 16;
}
__device__ __forceinline__ uint32_t pk2bf(float lo, float hi) {
  return f2bf(lo) | (f2bf(hi) << 16);
}

// ---------------------------------------------------------------------------
// Kernel 1: router (fp32 exact) + x -> bf16 conversion. Wave-per-token.
// Counters padded one per cacheline (single-line atomics serialized = 85us).
// ---------------------------------------------------------------------------
__global__ __launch_bounds__(256) void router_kernel(
    const float* __restrict__ x, const float* __restrict__ rw,
    uint16_t* __restrict__ xbf, int* __restrict__ counts,
    int* __restrict__ tokens, float* __restrict__ wts) {
  const int t = blockIdx.x * 4 + (threadIdx.x >> 6);  // token = wave id
  const int lane = threadIdx.x & 63;

  float4 xv[4];
  float acc[E_NUM];
#pragma unroll
  for (int e = 0; e < E_NUM; ++e) acc[e] = 0.f;

#pragma unroll
  for (int rep = 0; rep < 4; ++rep) {
    const int h0 = rep * 256 + lane * 4;
    xv[rep] = *(const float4*)(x + (size_t)t * H_DIM + h0);
    uint2 p;
    p.x = pk2bf(xv[rep].x, xv[rep].y);
    p.y = pk2bf(xv[rep].z, xv[rep].w);
    *(uint2*)(xbf + (size_t)t * H_DIM + h0) = p;
  }

#pragma unroll
  for (int e = 0; e < E_NUM; ++e) {
#pragma unroll
    for (int rep = 0; rep < 4; ++rep) {
      const float4 rv = *(const float4*)(rw + (size_t)e * H_DIM + rep * 256 + lane * 4);
      acc[e] += xv[rep].x * rv.x + xv[rep].y * rv.y + xv[rep].z * rv.z +
                xv[rep].w * rv.w;
    }
  }

#pragma unroll
  for (int e = 0; e < E_NUM; ++e) {
    float v = acc[e];
#pragma unroll
    for (int off = 32; off > 0; off >>= 1) v += __shfl_xor(v, off);
    acc[e] = v;  // every lane now holds the full sum
  }

  if (lane < 2) {
    float s[E_NUM];
#pragma unroll
    for (int e = 0; e < E_NUM; ++e) s[e] = 1.f / (1.f + expf(-acc[e]));
    // top-2, ties -> lower index (matches lax.top_k)
    int i1 = 0;
    float v1 = s[0];
#pragma unroll
    for (int e = 1; e < E_NUM; ++e)
      if (s[e] > v1) { v1 = s[e]; i1 = e; }
    int i2 = -1;
    float v2 = -1.f;
#pragma unroll
    for (int e = 0; e < E_NUM; ++e)
      if (e != i1 && s[e] > v2) { v2 = s[e]; i2 = e; }
    const float inv = 1.f / (v1 + v2 + 1e-20f);
    const int pe = (lane == 0) ? i1 : i2;
    const float pw = ((lane == 0) ? v1 : v2) * inv;
    const int slot = atomicAdd(&counts[pe * CPAD], 1);
    tokens[pe * T_TOK + slot] = t;
    wts[pe * T_TOK + slot] = pw;
  }
}

// ---------------------------------------------------------------------------
// Kernel 2: exclusive prefix sum over the 16 (padded) expert counts.
// ---------------------------------------------------------------------------
__global__ void offsets_kernel(const int* __restrict__ counts,
                               int* __restrict__ offsets) {
  if (threadIdx.x == 0) {
    int a = 0;
    for (int e = 0; e < E_NUM; ++e) {
      offsets[e] = a;
      a += counts[e * CPAD];
    }
    offsets[E_NUM] = a;
  }
}

// ---------------------------------------------------------------------------
// GEMM structure (R6): BM=128 BN=64 BK=64, 256 thr (4 waves of 64m x 32n),
// DOUBLE-BUFFERED pipelined K-loop, one barrier per iter. Next tile's
// global_load_lds + fp32-B reg loads issue AFTER the barrier, so the
// barrier's vmcnt(0) only drains loads issued a full compute-phase earlier
// (R5 lesson: 1 block/CU + single-buffer = full latency exposed per iter,
// 14k cyc/iter). ~560 active blocks = 2.2/CU; 65 KB LDS = 2 resident.
//
// LDS chunk swizzle: chunk(m,kq) at index m*8 + (kq ^ (m&7)) — spreads
// fragment b128 reads across bank groups (0 conflicts measured R4/R5).
// ---------------------------------------------------------------------------

// ---------------------------------------------------------------------------
// Kernel 3: GEMM1  h = silu(x@gateT) * (x@upT) * route_wt   (per expert)
// ---------------------------------------------------------------------------
__global__ __launch_bounds__(256, 2) void gemm1_kernel(
    const uint16_t* __restrict__ xbf, const float* __restrict__ gate,
    const float* __restrict__ up, const int* __restrict__ counts,
    const int* __restrict__ offsets, const int* __restrict__ tokens,
    const float* __restrict__ wts, uint16_t* __restrict__ hbuf) {
  const int e = blockIdx.z;
  const int count = counts[e * CPAD];
  const int m0 = blockIdx.y * 128;
  if (m0 >= count) return;
  const int n0 = blockIdx.x * 64;

  __shared__ __align__(16) uint16_t As[2][128 * 64];  // 2 x 16 KB
  __shared__ __align__(16) uint16_t Bgs[2][64 * 64];  // 2 x 8 KB
  __shared__ __align__(16) uint16_t Bus[2][64 * 64];  // 2 x 8 KB
  __shared__ int tok_s[128];
  __shared__ float wt_s[128];

  const int tid = threadIdx.x;
  if (tid < 128) {
    const int slot = m0 + tid;
    int tk = 0;
    float w = 0.f;
    if (slot < count) {
      tk = tokens[e * T_TOK + slot];
      w = wts[e * T_TOK + slot];
    }
    tok_s[tid] = tk;
    wt_s[tid] = w;
  }
  __syncthreads();

  // A: 1024 16B chunks, 4/thread (c = j*256+tid); dst = uniform + lane*16
  const uint16_t* a_g[4];
  uint32_t a_lo[4];
#pragma unroll
  for (int j = 0; j < 4; ++j) {
    const int c = j * 256 + tid;
    const int m = c >> 3;
    const int kq = (c & 7) ^ (m & 7);
    a_g[j] = xbf + (size_t)tok_s[m] * H_DIM + kq * 8;
    a_lo[j] = c * 8;
  }
  // B: 512 chunks per matrix, 2/thread
  const float* g_g[2];
  const float* u_g[2];
  uint32_t b_lo[2];
#pragma unroll
  for (int j = 0; j < 2; ++j) {
    const int c = j * 256 + tid;
    const int bm = c >> 3;
    const int kq = (c & 7) ^ (bm & 7);
    g_g[j] = gate + ((size_t)e * I_DIM + n0 + bm) * H_DIM + kq * 8;
    u_g[j] = up + ((size_t)e * I_DIM + n0 + bm) * H_DIM + kq * 8;
    b_lo[j] = c * 8;
  }

  const int wave = tid >> 6, lane = tid & 63;
  const int wm = (wave & 1) * 64, wn = (wave >> 1) * 32;
  const int lc = lane & 15, lq = lane >> 4;
  const int l7 = lc & 7;

  f32x4 accg[4][2], accu[4][2];
  const f32x4 zero4 = {0.f, 0.f, 0.f, 0.f};
#pragma unroll
  for (int i = 0; i < 4; ++i)
#pragma unroll
    for (int j = 0; j < 2; ++j) {
      accg[i][j] = zero4;
      accu[i][j] = zero4;
    }

  int am[4], bn[2];
#pragma unroll
  for (int i = 0; i < 4; ++i) am[i] = (wm + i * 16 + lc) * 64;
#pragma unroll
  for (int i = 0; i < 2; ++i) bn[i] = (wn + i * 16 + lc) * 64;

  // prologue: B(0) into regs, A(0) async into As[0]
  float4 gr[2][2], ur[2][2];
#pragma unroll
  for (int j = 0; j < 2; ++j) {
    gr[j][0] = *(const float4*)g_g[j];
    gr[j][1] = *(const float4*)(g_g[j] + 4);
    ur[j][0] = *(const float4*)u_g[j];
    ur[j][1] = *(const float4*)(u_g[j] + 4);
  }
#pragma unroll
  for (int j = 0; j < 4; ++j) async_copy16(a_g[j], &As[0][a_lo[j]]);

  for (int k0 = 0; k0 < H_DIM; k0 += 64) {
    const int buf = (k0 >> 6) & 1;
    // pack B(k0) regs -> LDS[buf] (other waves may still compute buf^1: safe)
#pragma unroll
    for (int j = 0; j < 2; ++j) {
      uint4 p;
      p.x = pk2bf(gr[j][0].x, gr[j][0].y);
      p.y = pk2bf(gr[j][0].z, gr[j][0].w);
      p.z = pk2bf(gr[j][1].x, gr[j][1].y);
      p.w = pk2bf(gr[j][1].z, gr[j][1].w);
      *(uint4*)&Bgs[buf][b_lo[j]] = p;
      p.x = pk2bf(ur[j][0].x, ur[j][0].y);
      p.y = pk2bf(ur[j][0].z, ur[j][0].w);
      p.z = pk2bf(ur[j][1].x, ur[j][1].y);
      p.w = pk2bf(ur[j][1].z, ur[j][1].w);
      *(uint4*)&Bus[buf][b_lo[j]] = p;
    }
    __syncthreads();  // drains asyncA(k0) (issued one compute-phase ago)
    if (k0 + 64 < H_DIM) {  // issue NEXT tile after the barrier
#pragma unroll
      for (int j = 0; j < 2; ++j) {
        gr[j][0] = *(const float4*)(g_g[j] + k0 + 64);
        gr[j][1] = *(const float4*)(g_g[j] + k0 + 68);
        ur[j][0] = *(const float4*)(u_g[j] + k0 + 64);
        ur[j][1] = *(const float4*)(u_g[j] + k0 + 68);
      }
#pragma unroll
      for (int j = 0; j < 4; ++j)
        async_copy16(a_g[j] + k0 + 64, &As[buf ^ 1][a_lo[j]]);
    }

#pragma unroll
    for (int ks = 0; ks < 2; ++ks) {
      const int kswz = ((ks * 4 + lq) ^ l7) * 8;
      bf16x8 af[4], bg[2], bu[2];
#pragma unroll
      for (int i = 0; i < 4; ++i)
        af[i] = *(const bf16x8*)&As[buf][am[i] + kswz];
#pragma unroll
      for (int i = 0; i < 2; ++i) {
        bg[i] = *(const bf16x8*)&Bgs[buf][bn[i] + kswz];
        bu[i] = *(const bf16x8*)&Bus[buf][bn[i] + kswz];
      }
#pragma unroll
      for (int im = 0; im < 4; ++im)
#pragma unroll
        for (int in = 0; in < 2; ++in) {
          accg[im][in] = __builtin_amdgcn_mfma_f32_16x16x32_bf16(
              af[im], bg[in], accg[im][in], 0, 0, 0);
          accu[im][in] = __builtin_amdgcn_mfma_f32_16x16x32_bf16(
              af[im], bu[in], accu[im][in], 0, 0, 0);
        }
    }
  }

  const int off_e = offsets[e];
#pragma unroll
  for (int im = 0; im < 4; ++im) {
#pragma unroll
    for (int r = 0; r < 4; ++r) {
      const int row = wm + im * 16 + lq * 4 + r;  // C/D: row=(lane>>4)*4+reg
      const int slot = m0 + row;
      if (slot < count) {
        const float w = wt_s[row];
        uint16_t* hrow = hbuf + (size_t)(off_e + slot) * I_DIM + n0 + wn;
#pragma unroll
        for (int in = 0; in < 2; ++in) {
          const float g = accg[im][in][r];
          const float u = accu[im][in][r];
          const float hv = g / (1.f + __expf(-g)) * u * w;
          hrow[in * 16 + lc] = (uint16_t)f2bf(hv);  // C/D: col=lane&15
        }
      }
    }
  }
}

// ---------------------------------------------------------------------------
// Kernel 4: GEMM2  out[tok] += h @ down_wT   (per expert, atomic combine)
// ---------------------------------------------------------------------------
__global__ __launch_bounds__(256, 2) void gemm2_kernel(
    const uint16_t* __restrict__ hbuf, const float* __restrict__ down,
    const int* __restrict__ counts, const int* __restrict__ offsets,
    const int* __restrict__ tokens, float* __restrict__ out) {
  const int e = blockIdx.z;
  const int count = counts[e * CPAD];
  const int m0 = blockIdx.y * 128;
  if (m0 >= count) return;
  const int n0 = blockIdx.x * 64;

  __shared__ __align__(16) uint16_t As[2][128 * 64];  // 2 x 16 KB
  __shared__ __align__(16) uint16_t Bs[2][64 * 64];   // 2 x 8 KB
  __shared__ int tok_s[128];

  const int tid = threadIdx.x;
  const int off_e = offsets[e];
  if (tid < 128) {
    const int slot = m0 + tid;
    tok_s[tid] = (slot < count) ? tokens[e * T_TOK + slot] : 0;
  }
  __syncthreads();

  const uint16_t* a_g[4];
  uint32_t a_lo[4];
#pragma unroll
  for (int j = 0; j < 4; ++j) {
    const int c = j * 256 + tid;
    const int m = c >> 3;
    const int kq = (c & 7) ^ (m & 7);
    int r = off_e + m0 + m;
    if (r > TOTAL_ROWS - 1) r = TOTAL_ROWS - 1;  // ragged tail: junk rows,
    a_g[j] = hbuf + (size_t)r * I_DIM + kq * 8;   // never stored
    a_lo[j] = c * 8;
  }
  const float* d_g[2];
  uint32_t b_lo[2];
#pragma unroll
  for (int j = 0; j < 2; ++j) {
    const int c = j * 256 + tid;
    const int bm = c >> 3;
    const int kq = (c & 7) ^ (bm & 7);
    d_g[j] = down + ((size_t)e * H_DIM + n0 + bm) * I_DIM + kq * 8;
    b_lo[j] = c * 8;
  }

  const int wave = tid >> 6, lane = tid & 63;
  const int wm = (wave & 1) * 64, wn = (wave >> 1) * 32;
  const int lc = lane & 15, lq = lane >> 4;
  const int l7 = lc & 7;

  f32x4 acc[4][2];
  const f32x4 zero4 = {0.f, 0.f, 0.f, 0.f};
#pragma unroll
  for (int i = 0; i < 4; ++i)
#pragma unroll
    for (int j = 0; j < 2; ++j) acc[i][j] = zero4;

  int am[4], bn[2];
#pragma unroll
  for (int i = 0; i < 4; ++i) am[i] = (wm + i * 16 + lc) * 64;
#pragma unroll
  for (int i = 0; i < 2; ++i) bn[i] = (wn + i * 16 + lc) * 64;

  float4 dr[2][2];
#pragma unroll
  for (int j = 0; j < 2; ++j) {
    dr[j][0] = *(const float4*)d_g[j];
    dr[j][1] = *(const float4*)(d_g[j] + 4);
  }
#pragma unroll
  for (int j = 0; j < 4; ++j) async_copy16(a_g[j], &As[0][a_lo[j]]);

  for (int k0 = 0; k0 < I_DIM; k0 += 64) {
    const int buf = (k0 >> 6) & 1;
#pragma unroll
    for (int j = 0; j < 2; ++j) {
      uint4 p;
      p.x = pk2bf(dr[j][0].x, dr[j][0].y);
      p.y = pk2bf(dr[j][0].z, dr[j][0].w);
      p.z = pk2bf(dr[j][1].x, dr[j][1].y);
      p.w = pk2bf(dr[j][1].z, dr[j][1].w);
      *(uint4*)&Bs[buf][b_lo[j]] = p;
    }
    __syncthreads();
    if (k0 + 64 < I_DIM) {
#pragma unroll
      for (int j = 0; j < 2; ++j) {
        dr[j][0] = *(const float4*)(d_g[j] + k0 + 64);
        dr[j][1] = *(const float4*)(d_g[j] + k0 + 68);
      }
#pragma unroll
      for (int j = 0; j < 4; ++j)
        async_copy16(a_g[j] + k0 + 64, &As[buf ^ 1][a_lo[j]]);
    }

#pragma unroll
    for (int ks = 0; ks < 2; ++ks) {
      const int kswz = ((ks * 4 + lq) ^ l7) * 8;
      bf16x8 af[4], bf[2];
#pragma unroll
      for (int i = 0; i < 4; ++i)
        af[i] = *(const bf16x8*)&As[buf][am[i] + kswz];
#pragma unroll
      for (int i = 0; i < 2; ++i)
        bf[i] = *(const bf16x8*)&Bs[buf][bn[i] + kswz];
#pragma unroll
      for (int im = 0; im < 4; ++im)
#pragma unroll
        for (int in = 0; in < 2; ++in)
          acc[im][in] = __builtin_amdgcn_mfma_f32_16x16x32_bf16(
              af[im], bf[in], acc[im][in], 0, 0, 0);
    }
  }

#pragma unroll
  for (int im = 0; im < 4; ++im) {
#pragma unroll
    for (int r = 0; r < 4; ++r) {
      const int row = wm + im * 16 + lq * 4 + r;
      const int slot = m0 + row;
      if (slot < count) {
        float* orow = out + (size_t)tok_s[row] * H_DIM + n0 + wn;
#pragma unroll
        for (int in = 0; in < 2; ++in)
          atomicAdd(orow + in * 16 + lc, acc[im][in][r]);
      }
    }
  }
}

// ---------------------------------------------------------------------------
extern "C" void kernel_launch(void* const* d_in, const int* in_sizes, int n_in,
                              void* d_out, int out_size, void* d_ws,
                              size_t ws_size, hipStream_t stream) {
  const float* x = (const float*)d_in[0];
  const float* rw = (const float*)d_in[1];
  const float* gate = (const float*)d_in[2];
  const float* up = (const float*)d_in[3];
  const float* down = (const float*)d_in[4];
  float* out = (float*)d_out;

  uint8_t* ws = (uint8_t*)d_ws;
  int* counts = (int*)ws;                                  // 16 * 64B padded
  int* offsets = (int*)(ws + 2048);                        // 17 ints
  int* tokens = (int*)(ws + 4096);                         // 128 KiB
  float* wts = (float*)(ws + 4096 + 131072);               // 128 KiB
  uint16_t* xbf = (uint16_t*)(ws + 4096 + 262144);         // 4 MiB
  uint16_t* hbuf = (uint16_t*)(ws + 4096 + 262144 + 4194304);  // 8 MiB

  hipMemsetAsync(counts, 0, 2048, stream);
  hipMemsetAsync(out, 0, (size_t)out_size * sizeof(float), stream);

  router_kernel<<<512, 256, 0, stream>>>(x, rw, xbf, counts, tokens, wts);
  offsets_kernel<<<1, 64, 0, stream>>>(counts, offsets);
  gemm1_kernel<<<dim3(16, 16, 16), 256, 0, stream>>>(
      xbf, gate, up, counts, offsets, tokens, wts, hbuf);
  gemm2_kernel<<<dim3(16, 16, 16), 256, 0, stream>>>(hbuf, down, counts,
                                                     offsets, tokens, out);
}